// Round 1
// baseline (165.241 us; speedup 1.0000x reference)
//
#include <hip/hip_runtime.h>
#include <cstddef>

// B=16, h=8, Ch=32, H=W=56, N=3136
//   heads 0-1 -> 3x3 (w3,b3), cbase hh*32
//   heads 2-4 -> 5x5 (w5,b5), cbase hh*32-64
//   heads 5-7 -> 7x7 (w7,b7), cbase hh*32-160
// out[b][n][hh*32+ch] = q[b][hh][n][ch] * dwconv(v)[b][hh][n][ch]
//
// R5 structure: per-wave-private LDS row staging. All global reads are
// contiguous 1-KB wave bursts (lane*16B); conv window is read from LDS.
// R6: pads cut 8->4 px (BUF_PX 72->64): LDS 43.5->39.0 KB => 4 blocks/CU
//     (16 waves/CU, was 12) — kernel is latency-bound (VALUBusy 16%,
//     HBM 25%, Occ 23%), so occupancy is the lever. Also prefetch the
//     q row before the conv loop so the epilogue multiply doesn't pay
//     a serial global-load latency chain.

#define BH 16
#define NH 8
#define CH 32
#define HW 56
#define NN (HW*HW)
#define ROWB (HW*CH*4)          // 7168 B per image row
#define BUF_PX 64               // px slots cover px -4..59 (slot = px+4)
#define BUF_FLOATS (BUF_PX*CH)  // 2048 floats = 8192 B per wave buffer

typedef float f32x4 __attribute__((ext_vector_type(4)));
typedef unsigned int u32x4 __attribute__((ext_vector_type(4)));

__device__ __forceinline__ f32x4 bload(__amdgpu_buffer_rsrc_t rs, int voff) {
    u32x4 u = __builtin_amdgcn_raw_buffer_load_b128(rs, voff, 0, 0);
    f32x4 f; __builtin_memcpy(&f, &u, 16); return f;
}

template<int K>
__device__ __forceinline__ void run_head(
    const float* __restrict__ q, const float* __restrict__ v,
    const float* __restrict__ w, const float* __restrict__ bias,
    float* __restrict__ out, int b, int hh, int y0, int cbase,
    float* __restrict__ w_lds, float* __restrict__ bufs)
{
    constexpr int P = K / 2;
    constexpr int NR = 7 + K - 1;       // window width in px per output strip
    const int t = threadIdx.x;

    // Stage weights into LDS, layout [tap][c].
    const int nw = K * K * CH;
    for (int i = t; i < nw; i += 256) {
        int tap = i >> 5, c = i & 31;
        w_lds[tap * CH + c] = w[(cbase + c) * (K * K) + tap];
    }
    __syncthreads();                    // only barrier in the kernel

    const int wid  = t >> 6;            // wave id = row within 4-row group
    const int lane = t & 63;
    float* wb = bufs + wid * BUF_FLOATS;   // wave-PRIVATE buffer: no barriers

    // Permanent zero x-pads: slots 0..3 (px -4..-1) and 60..63 (px 56..59).
    // Conv zero-padding in x comes from these; they are never overwritten.
    // (K=7 needs only 3 px of pad each side; 4 keeps 128B slot alignment.)
    {
        f32x4 z = {0.f, 0.f, 0.f, 0.f};
        const int half = lane & 31;
        float* zb = (lane < 32) ? wb : (wb + 60 * CH);
        *(f32x4*)(zb + half * 4) = z;   // 2 x 512 B
    }

    const int y    = y0 + wid;
    const int xseg = lane >> 3;         // compute mapping: 8 x-strips
    const int chq  = lane & 7;          //                  8 ch-quads
    const int x0   = xseg * 7;
    const int ch   = chq * 4;

    const size_t plane = ((size_t)b * NH + hh) * (size_t)NN * CH;
    const float* vb   = v + plane;
    const float* qrow = q + plane + (size_t)y * (HW * CH);

    f32x4 bias4 = *(const f32x4*)(bias + cbase + ch);
    f32x4 acc[7];
#pragma unroll
    for (int i = 0; i < 7; ++i) acc[i] = bias4;

    // Prefetch the q row now (contiguous 1-KB bursts); consumed in the
    // epilogue. 28 VGPRs, hides the q-load latency under the conv loop.
    f32x4 qf[7];
#pragma unroll
    for (int k = 0; k < 7; ++k)
        qf[k] = *(const f32x4*)(qrow + k * 256 + lane * 4);

#pragma unroll
    for (int dy = 0; dy < K; ++dy) {
        const int yy = y + dy - P;
        const bool ok = (unsigned)yy < (unsigned)HW;
        const float* base = vb + (ptrdiff_t)yy * (HW * CH);
        // OOB row -> num_records=0 -> loads return 0 (y zero-padding, proven R2-R4)
        __amdgpu_buffer_rsrc_t rs = __builtin_amdgcn_make_buffer_rsrc(
            (void*)base, (short)0, ok ? ROWB : 0, 0x00020000);

        // 7 CONTIGUOUS 1-KB wave loads cover the full row (no scatter).
        f32x4 ld[7];
#pragma unroll
        for (int k = 0; k < 7; ++k) ld[k] = bload(rs, k * 1024 + lane * 16);
#pragma unroll
        for (int k = 0; k < 7; ++k)
            *(f32x4*)(wb + k * 256 + 128 + lane * 4) = ld[k];  // slots 4..59

        // Register window from LDS: one base reg, imm offsets, reused over dx.
        f32x4 r[NR];
        const float* rb = wb + (size_t)(x0 - P + 4) * CH + ch;
#pragma unroll
        for (int j = 0; j < NR; ++j)
            r[j] = *(const f32x4*)(rb + j * CH);

#pragma unroll
        for (int dx = 0; dx < K; ++dx) {
            const f32x4 w4 = *(const f32x4*)(w_lds + (dy * K + dx) * CH + ch);
#pragma unroll
            for (int i = 0; i < 7; ++i)
                acc[i] += r[i + dx] * w4;
        }
    }

    // Epilogue: park conv results in wb to switch lane mapping, so q loads
    // are contiguous 1-KB bursts too; then multiply and store.
#pragma unroll
    for (int i = 0; i < 7; ++i)
        *(f32x4*)(wb + (size_t)(x0 + i + 4) * CH + ch) = acc[i];

    float* orow = out + ((size_t)b * NN + (size_t)y * HW) * (NH * CH) + hh * CH;
    const int px_l = lane >> 3;
    const int chl  = (lane & 7) * 4;
#pragma unroll
    for (int k = 0; k < 7; ++k) {
        const f32x4 c4 = *(const f32x4*)(wb + (size_t)(k * 8 + px_l + 4) * CH + chl);
        const f32x4 o  = c4 * qf[k];
        *(f32x4*)(orow + (size_t)(k * 8 + px_l) * (NH * CH) + chl) = o;
    }
}

__global__ __launch_bounds__(256, 4)   // 39.0 KB LDS -> 4 blocks/CU, 128 VGPR cap
void clusterformer_fused(const float* __restrict__ q, const float* __restrict__ v,
                         const float* __restrict__ w3, const float* __restrict__ b3,
                         const float* __restrict__ w5, const float* __restrict__ b5,
                         const float* __restrict__ w7, const float* __restrict__ b7,
                         float* __restrict__ out)
{
    __shared__ __align__(16) float bufs[4 * BUF_FLOATS]; // 32768 B
    __shared__ __align__(16) float w_lds[49 * CH];       // 6272 B

    // bid -> (plane p, ygroup): XCD-local planes (R3: FETCH 75->53 MB) and
    // heavy heads (K7) first for tail balance.
    const int bid  = blockIdx.x;
    const int p_lo = bid & 7;
    const int t2   = bid >> 3;         // 0..223
    const int p_hi = t2 / 14;
    const int yg   = t2 % 14;
    const int p    = p_hi * 8 + p_lo;  // 0..127
    const int b    = p & 15;
    const int hhp  = p >> 4;           // dispatch-ordered head
    const int hh   = (hhp < 3) ? (5 + hhp) : ((hhp < 6) ? (hhp - 1) : (hhp - 6));
    const int y0   = yg * 4;

    if (hh < 2)      run_head<3>(q, v, w3, b3, out, b, hh, y0, hh * 32,       w_lds, bufs);
    else if (hh < 5) run_head<5>(q, v, w5, b5, out, b, hh, y0, hh * 32 - 64,  w_lds, bufs);
    else             run_head<7>(q, v, w7, b7, out, b, hh, y0, hh * 32 - 160, w_lds, bufs);
}

extern "C" void kernel_launch(void* const* d_in, const int* in_sizes, int n_in,
                              void* d_out, int out_size, void* d_ws, size_t ws_size,
                              hipStream_t stream) {
    const float* q  = (const float*)d_in[0];
    const float* v  = (const float*)d_in[1];
    const float* w3 = (const float*)d_in[2];
    const float* b3 = (const float*)d_in[3];
    const float* w5 = (const float*)d_in[4];
    const float* b5 = (const float*)d_in[5];
    const float* w7 = (const float*)d_in[6];
    const float* b7 = (const float*)d_in[7];
    float* out = (float*)d_out;

    const int grid = BH * NH * 14;     // 1792 blocks of 256 threads
    clusterformer_fused<<<grid, 256, 0, stream>>>(q, v, w3, b3, w5, b5, w7, b7, out);
}